// Round 1
// 450.341 us; speedup vs baseline: 1.0081x; 1.0081x over previous
//
#include <hip/hip_runtime.h>
#include <math.h>

#define BB 64
#define DD 8732
#define CC 81
#define NN 50
#define TROWS 64                    // rows per tile
#define TFL4  1296                  // 64*81/4 float4 per tile (20736 B)
#define CE_GRID 1024                // 4 blocks/CU
#define NTILES (BB * DD / TROWS)    // 8732 exactly

// ---------------- k_match: per-prior best-IoU gt, conf_t, smooth-L1 ----------
// v2: no LDS staging. tboxes reads are block-uniform -> scalar s_load into
// SGPRs; n-loop unrolled x10 so the 10 independent IEEE divides pipeline
// (only the cheap cmp/cndmask max-update is loop-carried). d clamped so all
// lanes execute uniformly; writes and loss contribution guarded by `active`.
__global__ __launch_bounds__(256) void k_match(
    const float* __restrict__ loc_data,   // [B,D,4]
    const float* __restrict__ dboxes,     // [D,4]
    const float* __restrict__ tboxes,     // [B,N,4]
    const int*   __restrict__ tlabels,    // [B,N]
    unsigned char* __restrict__ conf_t,   // [B,D]
    int* __restrict__ num_pos,            // [B]  (pre-zeroed)
    float* __restrict__ acc)              // [0]=loss_l, [1]=loss_c (pre-zeroed)
{
    const int b   = blockIdx.y;
    const int tid = threadIdx.x;
    const int d   = blockIdx.x * 256 + tid;
    const bool active = (d < DD);
    const int dc  = active ? d : (DD - 1);         // clamp: uniform execution

    const float* __restrict__ tb = tboxes + b * (NN * 4);  // uniform -> s_load

    const float4 db = ((const float4*)dboxes)[dc];
    const float dx1 = db.x, dy1 = db.y, dx2 = db.z, dy2 = db.w;
    const float dArea = (dx1 - dx2) * (dy1 - dy2);

    float bestIoU = -1.0f;
    int   bestN   = 0;
    #pragma unroll 10
    for (int n = 0; n < NN; n++) {
        const float tx1 = tb[n * 4 + 0];
        const float ty1 = tb[n * 4 + 1];
        const float tx2 = tb[n * 4 + 2];
        const float ty2 = tb[n * 4 + 3];
        const float area = (tx1 - tx2) * (ty1 - ty2);   // == reference _area
        const float lx = fmaxf(tx1, dx1), ly = fmaxf(ty1, dy1);
        const float rx = fminf(tx2, dx2), ry = fminf(ty2, dy2);
        const float w = fmaxf(rx - lx, 0.0f), h = fmaxf(ry - ly, 0.0f);
        const float inter = w * h;
        const float iou = inter / (area + dArea - inter);  // IEEE, as reference
        if (iou > bestIoU) { bestIoU = iou; bestN = n; }   // first-max = argmax
    }

    int ct = 0;
    if (!(bestIoU < 0.5f)) ct = tlabels[b * NN + bestN] + 1;
    const bool pos = active && (ct > 0);
    if (active) conf_t[(size_t)b * DD + d] = (unsigned char)ct;

    float ll = 0.0f;
    if (pos) {
        const float bx1 = tb[bestN * 4 + 0], by1 = tb[bestN * 4 + 1];
        const float bx2 = tb[bestN * 4 + 2], by2 = tb[bestN * 4 + 3];
        const float dw = dx2 - dx1, dh = dy2 - dy1;
        const float t0 = ((bx1 - dx1) + (bx2 - dx2)) * 0.5f * 10.0f / dw;
        const float t1 = ((by1 - dy1) + (by2 - dy2)) * 0.5f * 10.0f / dh;
        const float t2 = __logf((bx2 - bx1) / dw) * 5.0f;
        const float t3 = __logf((by2 - by1) / dh) * 5.0f;
        const float4 ld = ((const float4*)loc_data)[(size_t)b * DD + d];
        float xs[4] = {ld.x - t0, ld.y - t1, ld.z - t2, ld.w - t3};
        #pragma unroll
        for (int k = 0; k < 4; k++) {
            float ax = fabsf(xs[k]);
            ll += (ax < 1.0f) ? 0.5f * xs[k] * xs[k] : ax - 0.5f;
        }
    }
    for (int off = 32; off > 0; off >>= 1) ll += __shfl_down(ll, off);
    unsigned long long bal = __ballot(pos);
    if ((tid & 63) == 0) {
        if (ll != 0.0f) atomicAdd(&acc[0], ll);
        int c = (int)__popcll(bal);
        if (c) atomicAdd(&num_pos[b], c);
    }
}

// ---------------- k_ce: LDS tile staging, named-reg prefetch (no arrays) -----
// Tile = 64 rows (20736 B). LOAD issues 6 wide coalesced float4 reads into
// NAMED registers r0..r5; they are stored to LDS at the top of the next
// iteration, so the global loads stay in flight across the compute phase.
__global__ __launch_bounds__(256) void k_ce(
    const float* __restrict__ conf_data,      // [B,D,C]
    const unsigned char* __restrict__ conf_t, // [B,D]
    float* __restrict__ ce_mined,             // [B*D] (positives zeroed)
    float* __restrict__ acc)
{
    __shared__ float4 sbuf[TFL4];             // 20736 B
    const int tid  = threadIdx.x;
    const int lane = tid & 63;
    const int w    = tid >> 6;        // wave in block (0..3)
    const int q    = lane >> 4;       // quarter (0..3)
    const int s    = lane & 15;       // sublane within quarter

    float4 r0, r1, r2, r3, r4, r5;
    float lc = 0.0f;

    int t = blockIdx.x;
    {
        const float4* src = (const float4*)conf_data + (size_t)t * TFL4;
        r0 = src[tid];
        r1 = src[tid + 256];
        r2 = src[tid + 512];
        r3 = src[tid + 768];
        r4 = src[tid + 1024];
        if (tid < 16) r5 = src[1280 + tid];
    }
    for (; t < NTILES; t += CE_GRID) {
        __syncthreads();                      // prior compute done; LDS reusable
        sbuf[tid]        = r0;                // vmcnt wait lands here
        sbuf[tid + 256]  = r1;
        sbuf[tid + 512]  = r2;
        sbuf[tid + 768]  = r3;
        sbuf[tid + 1024] = r4;
        if (tid < 16) sbuf[1280 + tid] = r5;
        const int tn = t + CE_GRID;
        if (tn < NTILES) {                    // issue next tile's loads NOW
            const float4* src = (const float4*)conf_data + (size_t)tn * TFL4;
            r0 = src[tid];
            r1 = src[tid + 256];
            r2 = src[tid + 512];
            r3 = src[tid + 768];
            r4 = src[tid + 1024];
            if (tid < 16) r5 = src[1280 + tid];
        }
        __syncthreads();                      // tile t visible in LDS

        const float* sb = (const float*)sbuf;
        #pragma unroll
        for (int i = 0; i < 4; i++) {
            const int lr = w * 16 + i * 4 + q;        // local row 0..63
            const float* row = sb + lr * CC;
            float x0 = row[s];
            float x1 = row[s + 16];
            float x2 = row[s + 32];
            float x3 = row[s + 48];
            float x4 = row[s + 64];
            float x5 = (s == 0) ? row[80] : 0.0f;
            const int r = t * TROWS + lr;
            const int ct = conf_t[r];

            float e = __expf(x0) + __expf(x1) + __expf(x2) + __expf(x3) + __expf(x4);
            if (s == 0) e += __expf(x5);

            const int k  = ct >> 4;
            const int sl = ct & 15;
            float xv = (k == 0) ? x0 : (k == 1) ? x1 : (k == 2) ? x2
                     : (k == 3) ? x3 : (k == 4) ? x4 : x5;
            float v = (s == sl) ? xv : 0.0f;

            #pragma unroll
            for (int off = 1; off < 16; off <<= 1) {
                e += __shfl_xor(e, off);
                v += __shfl_xor(v, off);
            }
            if (s == 0) {
                float ce = fmaxf(__logf(e) - v, 0.0f);
                bool pos = (ct > 0);
                ce_mined[r] = pos ? 0.0f : ce;
                if (pos) lc += ce;
            }
        }
    }
    #pragma unroll
    for (int off = 32; off > 0; off >>= 1) lc += __shfl_down(lc, off);
    if (lane == 0 && lc != 0.0f) atomicAdd(&acc[1], lc);
}

// ---------------- k_tail: per-batch top-K sum + last-block finalize ----------
// K-th largest via binary search on float bit patterns (values >= 0);
// sum(topK) = sum(v > vK) + (K - cnt_gt)*vK -- exact, tie-order invariant.
__global__ __launch_bounds__(256) void k_tail(
    const float* __restrict__ ce_mined,   // [B*D]
    const int*   __restrict__ num_pos,    // [B]
    float* __restrict__ acc,              // [2]
    int*   __restrict__ done,             // [1]  (pre-zeroed)
    float* __restrict__ out)              // [2]
{
    const int b   = blockIdx.x;
    const int tid = threadIdx.x;
    const int K   = min(3 * num_pos[b], DD);
    __shared__ int   s_cnt;
    __shared__ float s_sum;

    const float* rowm = ce_mined + (size_t)b * DD;
    unsigned vv[35];                      // 35*256 = 8960 >= 8732
    #pragma unroll
    for (int j = 0; j < 35; j++) {
        int i = tid + j * 256;
        vv[j] = (i < DD) ? __float_as_uint(rowm[i]) : 0u;
    }

    if (K > 0) {                          // uniform per block
        unsigned lo = 0u, hi = 0x7F800000u;
        while (lo < hi) {
            unsigned mid = lo + ((hi - lo) >> 1);
            int c = 0;
            #pragma unroll
            for (int j = 0; j < 35; j++) c += (vv[j] > mid) ? 1 : 0;
            for (int off = 32; off > 0; off >>= 1) c += __shfl_down(c, off);
            if (tid == 0) s_cnt = 0;
            __syncthreads();
            if ((tid & 63) == 0) atomicAdd(&s_cnt, c);
            __syncthreads();
            if (s_cnt >= K) lo = mid + 1; else hi = mid;
            __syncthreads();
        }
        const unsigned ustar = lo;
        const float thr = __uint_as_float(ustar);
        float sum = 0.0f; int cgt = 0;
        #pragma unroll
        for (int j = 0; j < 35; j++) {
            if (vv[j] > ustar) { sum += __uint_as_float(vv[j]); cgt++; }
        }
        for (int off = 32; off > 0; off >>= 1) {
            sum += __shfl_down(sum, off);
            cgt += __shfl_down(cgt, off);
        }
        if (tid == 0) { s_sum = 0.0f; s_cnt = 0; }
        __syncthreads();
        if ((tid & 63) == 0) { atomicAdd(&s_sum, sum); atomicAdd(&s_cnt, cgt); }
        __syncthreads();
        if (tid == 0) atomicAdd(&acc[1], s_sum + (float)(K - s_cnt) * thr);
    }
    __syncthreads();

    if (tid == 0) {
        __threadfence();                       // my acc[1] add visible before done++
        int old = atomicAdd(done, 1);          // device-scope
        if (old == BB - 1) {                   // last block: all adds complete
            __threadfence();
            int np = 0;
            for (int i = 0; i < BB; i++) np += num_pos[i];
            float l0 = acc[0];
            float l1 = atomicAdd(&acc[1], 0.0f);            // atomic read (RMW)
            float Nt = (float)np;
            out[0] = l0 / Nt;
            out[1] = l1 / Nt;
        }
    }
}

extern "C" void kernel_launch(void* const* d_in, const int* in_sizes, int n_in,
                              void* d_out, int out_size, void* d_ws, size_t ws_size,
                              hipStream_t stream) {
    const float* loc_data  = (const float*)d_in[0];  // [64,8732,4]
    const float* conf_data = (const float*)d_in[1];  // [64,8732,81]
    const float* dboxes    = (const float*)d_in[2];  // [8732,4]
    const float* tboxes    = (const float*)d_in[3];  // [64,50,4]
    const int*   tlabels   = (const int*)d_in[4];    // [64,50]
    float* out = (float*)d_out;

    // ws: ce_mined[B*D] | conf_t[B*D] | num_pos[64] | acc[2] | done[1]
    float*         ce_mined = (float*)d_ws;
    unsigned char* conf_t   = (unsigned char*)(ce_mined + (size_t)BB * DD);
    int*           num_pos  = (int*)(conf_t + (size_t)BB * DD);   // B*D % 4 == 0
    float*         acc      = (float*)(num_pos + BB);
    int*           done     = (int*)(acc + 2);

    hipMemsetAsync(num_pos, 0, (BB + 3) * sizeof(int), stream);  // np + acc + done

    hipLaunchKernelGGL(k_match, dim3((DD + 255) / 256, BB), dim3(256), 0, stream,
                       loc_data, dboxes, tboxes, tlabels, conf_t, num_pos, acc);
    hipLaunchKernelGGL(k_ce, dim3(CE_GRID), dim3(256), 0, stream,
                       conf_data, conf_t, ce_mined, acc);
    hipLaunchKernelGGL(k_tail, dim3(BB), dim3(256), 0, stream,
                       ce_mined, num_pos, acc, done, out);
}